// Round 1
// baseline (686.502 us; speedup 1.0000x reference)
//
#include <hip/hip_runtime.h>
#include <hip/hip_bf16.h>
#include <math.h>

#define CH 150
// volume: B=4, D=H=W=64; per-sample voxels = 64^3 = 262144 = 1<<18
// image layout (B,2,D,H,W): sample stride = 1<<19, channel stride = 1<<18

// ---------------- gate kernel: p = sigmoid( sum_c pw[c]*relu(conv3x3x3_c(x)+hb[c]) )
__global__ __launch_bounds__(256) void gate_kernel(
    const float* __restrict__ img,   // (4,2,64,64,64)
    const float* __restrict__ hw,    // (150,27)
    const float* __restrict__ hb,    // (150)
    const float* __restrict__ pw,    // (150)
    float* __restrict__ p)           // (4,64,64,64)
{
    int idx = blockIdx.x * 256 + threadIdx.x;
    int w = idx & 63;
    int h = (idx >> 6) & 63;
    int d = (idx >> 12) & 63;
    int b = idx >> 18;

    const float* x = img + ((size_t)b << 19);  // channel 0 of sample b

    // load 27-neighborhood (zero padding = SAME conv on zero-padded input)
    float n[27];
    int j = 0;
    #pragma unroll
    for (int dd = -1; dd <= 1; ++dd) {
        #pragma unroll
        for (int dh = -1; dh <= 1; ++dh) {
            #pragma unroll
            for (int dw = -1; dw <= 1; ++dw) {
                int z = d + dd, y = h + dh, xx = w + dw;
                bool ok = ((unsigned)z < 64u) & ((unsigned)y < 64u) & ((unsigned)xx < 64u);
                n[j++] = ok ? x[(z << 12) + (y << 6) + xx] : 0.0f;
            }
        }
    }

    float acc = 0.0f;
    for (int c = 0; c < CH; ++c) {
        float s = hb[c];
        const float* wc = hw + c * 27;
        #pragma unroll
        for (int k = 0; k < 27; ++k) s = fmaf(wc[k], n[k], s);
        s = fmaxf(s, 0.0f);
        acc = fmaf(pw[c], s, acc);
    }
    p[idx] = 1.0f / (1.0f + __expf(-acc));
}

// ---------------- extract r (channel 1) into dst
__global__ __launch_bounds__(256) void extract_r_kernel(
    const float* __restrict__ img, float* __restrict__ dst)
{
    int idx = blockIdx.x * 256 + threadIdx.x;
    int b = idx >> 18;
    int rem = idx & ((1 << 18) - 1);
    dst[idx] = img[((size_t)b << 19) + (1 << 18) + rem];
}

// ---------------- one propagation iteration: vout = max(vin, r + p*(maxpool3(vin) - r))
__global__ __launch_bounds__(256) void pool_iter_kernel(
    const float* __restrict__ vin,
    const float* __restrict__ img,
    const float* __restrict__ p,
    float* __restrict__ vout)
{
    int idx = blockIdx.x * 256 + threadIdx.x;
    int w = idx & 63;
    int h = (idx >> 6) & 63;
    int d = (idx >> 12) & 63;
    int b = idx >> 18;

    const float* vb = vin + ((size_t)b << 18);

    int d0 = d > 0 ? d - 1 : 0, d1 = d < 63 ? d + 1 : 63;
    int h0 = h > 0 ? h - 1 : 0, h1 = h < 63 ? h + 1 : 63;
    int w0 = w > 0 ? w - 1 : 0, w1 = w < 63 ? w + 1 : 63;

    float m = -INFINITY;
    for (int z = d0; z <= d1; ++z) {
        for (int y = h0; y <= h1; ++y) {
            const float* row = vb + (z << 12) + (y << 6);
            for (int xx = w0; xx <= w1; ++xx)
                m = fmaxf(m, row[xx]);
        }
    }

    float vc = vb[(d << 12) + (h << 6) + w];
    float r  = img[((size_t)b << 19) + (1 << 18) + (idx & ((1 << 18) - 1))];
    float pv = p[idx];
    vout[idx] = fmaxf(vc, fmaf(pv, m - r, r));
}

extern "C" void kernel_launch(void* const* d_in, const int* in_sizes, int n_in,
                              void* d_out, int out_size, void* d_ws, size_t ws_size,
                              hipStream_t stream) {
    const float* img = (const float*)d_in[0];   // (4,2,64,64,64)
    const float* hw  = (const float*)d_in[1];   // (150,1,3,3,3)
    const float* hb  = (const float*)d_in[2];   // (150,)
    const float* pw  = (const float*)d_in[3];   // (1,150,1,1,1)
    // d_in[4] = k (device scalar); reference uses k=30, hard-coded below.

    float* out = (float*)d_out;                     // (4,1,64,64,64) fp32
    float* p   = (float*)d_ws;                      // 4 MB
    float* vA  = (float*)((char*)d_ws + (4u << 20)); // 4 MB ping buffer

    const int total  = 4 * 64 * 64 * 64;  // 1048576
    const int blocks = total / 256;       // 4096

    gate_kernel<<<blocks, 256, 0, stream>>>(img, hw, hb, pw, p);

    // v0 = r, staged in d_out so that iteration 29 (odd) naturally ends in d_out
    extract_r_kernel<<<blocks, 256, 0, stream>>>(img, out);

    const float* cur = out;
    for (int i = 0; i < 30; ++i) {
        float* nxt = (i & 1) ? out : vA;    // i=29 (odd) -> d_out
        pool_iter_kernel<<<blocks, 256, 0, stream>>>(cur, img, p, nxt);
        cur = nxt;
    }
}

// Round 2
// 665.521 us; speedup vs baseline: 1.0315x; 1.0315x over previous
//
#include <hip/hip_runtime.h>
#include <math.h>

#define CH 150
#define NEG_INF (-__builtin_inff())

// ================= gate: p = sigmoid(sum_c pw[c]*relu(conv3x3x3(x)+hb[c]))
// 4 voxels per thread along x: each weight load feeds 4 FMAs.
__global__ __launch_bounds__(256) void gate_kernel(
    const float* __restrict__ img, const float* __restrict__ hw,
    const float* __restrict__ hb,  const float* __restrict__ pw,
    float* __restrict__ p)
{
    int t = blockIdx.x * 256 + threadIdx.x;     // 2^18 threads, 4 voxels each
    int w0 = (t & 15) << 2;
    int h  = (t >> 4) & 63;
    int d  = (t >> 10) & 63;
    int b  = t >> 16;
    const float* x = img + ((size_t)b << 19);   // channel 0 of sample b

    // neighborhood rows: 9 rows (dz,dy) x 6 floats covering x in [w0-1, w0+5)
    float n[9][6];
    #pragma unroll
    for (int dd = 0; dd < 3; ++dd) {
        #pragma unroll
        for (int dh = 0; dh < 3; ++dh) {
            int ri = dd * 3 + dh;
            int z = d + dd - 1, y = h + dh - 1;
            bool rv = ((unsigned)z < 64u) && ((unsigned)y < 64u);
            const float* row = x + (z << 12) + (y << 6) + w0;
            n[ri][0] = (rv && w0 > 0)  ? row[-1] : 0.f;
            n[ri][1] = rv ? row[0] : 0.f;
            n[ri][2] = rv ? row[1] : 0.f;
            n[ri][3] = rv ? row[2] : 0.f;
            n[ri][4] = rv ? row[3] : 0.f;
            n[ri][5] = (rv && w0 < 60) ? row[4] : 0.f;
        }
    }

    float a0 = 0.f, a1 = 0.f, a2 = 0.f, a3 = 0.f;
    for (int c = 0; c < CH; ++c) {
        const float* wc = hw + c * 27;          // wc[kd*9+kh*3+kw]
        float bias = hb[c];
        float s0 = bias, s1 = bias, s2 = bias, s3 = bias;
        #pragma unroll
        for (int ri = 0; ri < 9; ++ri) {
            #pragma unroll
            for (int kx = 0; kx < 3; ++kx) {
                float wv = wc[ri * 3 + kx];
                s0 = fmaf(wv, n[ri][kx + 0], s0);
                s1 = fmaf(wv, n[ri][kx + 1], s1);
                s2 = fmaf(wv, n[ri][kx + 2], s2);
                s3 = fmaf(wv, n[ri][kx + 3], s3);
            }
        }
        float g = pw[c];
        a0 = fmaf(g, fmaxf(s0, 0.f), a0);
        a1 = fmaf(g, fmaxf(s1, 0.f), a1);
        a2 = fmaf(g, fmaxf(s2, 0.f), a2);
        a3 = fmaf(g, fmaxf(s3, 0.f), a3);
    }
    float4 o;
    o.x = 1.f / (1.f + __expf(-a0));
    o.y = 1.f / (1.f + __expf(-a1));
    o.z = 1.f / (1.f + __expf(-a2));
    o.w = 1.f / (1.f + __expf(-a3));
    int base = (b << 18) + (d << 12) + (h << 6) + w0;
    *(float4*)(p + base) = o;
}

// ================= fused propagation: T iterations of v=max(v, r+p*(maxpool3(v)-r))
// Tile: 8(z) x 16(y) x 16(x) output, halo 4 -> cube 16x24x24 in LDS (36.9 KB).
// Iteration it updates local region [lo, dim-lo) with lo = 5-T+it; shrinking
// regions keep fused iterations exact. -inf fill reproduces reference padding.
#define CZ 16
#define CY 24
#define CX 24
#define PLANE (CY*CX)     // 576
#define CUBE  (CZ*PLANE)  // 9216

__device__ __forceinline__ void read_plane(const float* A, int zr, int lb, bool act,
                                           float& m, float& c)
{
    m = NEG_INF; c = NEG_INF;
    if (act) {
        int base = zr * PLANE + lb;
        float a0 = A[base - CX - 1], a1 = A[base - CX], a2 = A[base - CX + 1];
        float a3 = A[base - 1],      a4 = A[base],      a5 = A[base + 1];
        float a6 = A[base + CX - 1], a7 = A[base + CX], a8 = A[base + CX + 1];
        float m1 = fmaxf(fmaxf(a0, a1), fmaxf(a2, a3));
        float m2 = fmaxf(fmaxf(a5, a6), fmaxf(a7, a8));
        m = fmaxf(fmaxf(m1, m2), a4);
        c = a4;
    }
}

__global__ __launch_bounds__(256) void prop_kernel(
    const float* __restrict__ vin, int in_sstride,
    const float* __restrict__ rimg,   // img + (1<<18): r, sample stride 1<<19
    const float* __restrict__ p,
    float* __restrict__ vout,
    int T)
{
    __shared__ float A[CUBE];
    int blk = blockIdx.x;             // 512 blocks
    int b  = blk >> 7;
    int tz = ((blk >> 4) & 7) << 3;
    int ty = ((blk >> 2) & 3) << 4;
    int tx = (blk & 3) << 4;

    const float* vb = vin  + (size_t)b * in_sstride;
    const float* rb = rimg + ((size_t)b << 19);
    const float* pb = p    + ((size_t)b << 18);
    float*       ob = vout + ((size_t)b << 18);

    int tid = threadIdx.x;

    // ---- stage cube (origin tile-4 per axis), -inf outside volume
    for (int c = tid; c < CUBE; c += 256) {
        int cz  = c / PLANE;
        int rem = c - cz * PLANE;
        int cy  = rem / CX;
        int cx  = rem - cy * CX;
        int gz = tz + cz - 4, gy = ty + cy - 4, gx = tx + cx - 4;
        float v = NEG_INF;
        if (((unsigned)gz < 64u) && ((unsigned)gy < 64u) && ((unsigned)gx < 64u))
            v = vb[gz * 4096 + gy * 64 + gx];
        A[c] = v;
    }

    // ---- fixed lane->(py,px) plane mapping, 3 chunks of 256
    int  cpy[3], cpx[3];
    bool cact[3];
    #pragma unroll
    for (int k = 0; k < 3; ++k) {
        int i = tid + (k << 8);
        cact[k] = i < PLANE;
        int yy = i / CX;
        cpy[k] = yy;
        cpx[k] = i - yy * CX;
    }
    __syncthreads();

    for (int it = 0; it < T; ++it) {
        int lo  = 5 - T + it;
        int hiy = CY - lo;
        int hiz = CZ - lo;
        bool last_it = (it == T - 1);

        bool act[3], vxy[3];
        int  goff[3], lbase[3];
        #pragma unroll
        for (int k = 0; k < 3; ++k) {
            act[k] = cact[k] && cpy[k] >= lo && cpy[k] < hiy
                             && cpx[k] >= lo && cpx[k] < hiy;
            int gy = ty + cpy[k] - 4, gx = tx + cpx[k] - 4;
            vxy[k]  = ((unsigned)gy < 64u) && ((unsigned)gx < 64u);
            goff[k] = gy * 64 + gx;
            lbase[k] = cpy[k] * CX + cpx[k];
        }

        float mA[3], mB[3], mC[3], vP[3], vC[3];
        // prologue: planes lo-1 and lo
        #pragma unroll
        for (int k = 0; k < 3; ++k) {
            float dummy;
            read_plane(A, lo - 1, lbase[k], act[k], mA[k], dummy);
            read_plane(A, lo,     lbase[k], act[k], mB[k], vP[k]);
        }
        __syncthreads();

        for (int zr = lo + 1; zr <= hiz; ++zr) {
            int zu = zr - 1;
            int gz = tz + zu - 4;
            bool vz = (unsigned)gz < 64u;
            #pragma unroll
            for (int k = 0; k < 3; ++k) {
                read_plane(A, zr, lbase[k], act[k], mC[k], vC[k]);
                if (act[k]) {
                    float m3 = fmaxf(fmaxf(mA[k], mB[k]), mC[k]);
                    float vnew = NEG_INF;
                    if (vxy[k] && vz) {
                        int g = gz * 4096 + goff[k];
                        float rv = rb[g];
                        float pv = pb[g];
                        vnew = fmaxf(vP[k], fmaf(pv, m3 - rv, rv));
                        if (last_it) ob[g] = vnew;
                    }
                    A[zu * PLANE + lbase[k]] = vnew;
                }
                mA[k] = mB[k]; mB[k] = mC[k]; vP[k] = vC[k];
            }
            __syncthreads();
        }
    }
}

extern "C" void kernel_launch(void* const* d_in, const int* in_sizes, int n_in,
                              void* d_out, int out_size, void* d_ws, size_t ws_size,
                              hipStream_t stream) {
    const float* img = (const float*)d_in[0];   // (4,2,64,64,64)
    const float* hw  = (const float*)d_in[1];   // (150,27)
    const float* hb  = (const float*)d_in[2];   // (150,)
    const float* pw  = (const float*)d_in[3];   // (150,)
    // d_in[4] = k (device scalar); reference fixes k=30.

    float* out = (float*)d_out;                      // X buffer (4 MB)
    float* p   = (float*)d_ws;                       // 4 MB
    float* vA  = (float*)((char*)d_ws + (4u << 20)); // Y buffer (4 MB)

    gate_kernel<<<1024, 256, 0, stream>>>(img, hw, hb, pw, p);

    const float* r0 = img + (1 << 18);  // r channel base, sample stride 1<<19

    // 8 launches: T = 4*7 + 2 = 30 iterations. Ping-pong: Y,X,Y,X,... ends in X=d_out.
    prop_kernel<<<512, 256, 0, stream>>>(r0,  1 << 19, r0, p, vA,  4);  // img -> Y
    prop_kernel<<<512, 256, 0, stream>>>(vA,  1 << 18, r0, p, out, 4);  // Y -> X
    prop_kernel<<<512, 256, 0, stream>>>(out, 1 << 18, r0, p, vA,  4);  // X -> Y
    prop_kernel<<<512, 256, 0, stream>>>(vA,  1 << 18, r0, p, out, 4);
    prop_kernel<<<512, 256, 0, stream>>>(out, 1 << 18, r0, p, vA,  4);
    prop_kernel<<<512, 256, 0, stream>>>(vA,  1 << 18, r0, p, out, 4);
    prop_kernel<<<512, 256, 0, stream>>>(out, 1 << 18, r0, p, vA,  4);
    prop_kernel<<<512, 256, 0, stream>>>(vA,  1 << 18, r0, p, out, 2);  // Y -> X (=d_out)
}

// Round 3
// 398.360 us; speedup vs baseline: 1.7233x; 1.6707x over previous
//
#include <hip/hip_runtime.h>
#include <math.h>

#define CH 150
#define NEG_INF (-__builtin_inff())

// ================= gate: p = sigmoid(sum_c pw[c]*relu(conv3x3x3(x)+hb[c]))
// 4 voxels/thread along x. __launch_bounds__(256,2): allow up to 256 VGPR so
// the 54-float neighborhood stays in registers (R2: compiler spilled at VGPR=32).
__global__ __launch_bounds__(256, 2) void gate_kernel(
    const float* __restrict__ img, const float* __restrict__ hw,
    const float* __restrict__ hb,  const float* __restrict__ pw,
    float* __restrict__ p)
{
    int t = blockIdx.x * 256 + threadIdx.x;     // 2^18 threads, 4 voxels each
    int w0 = (t & 15) << 2;
    int h  = (t >> 4) & 63;
    int d  = (t >> 10) & 63;
    int b  = t >> 16;
    const float* x = img + ((size_t)b << 19);   // channel 0 of sample b

    // 9 rows (dz,dy) x 6 floats covering x in [w0-1, w0+5)
    float n[9][6];
    #pragma unroll
    for (int dd = 0; dd < 3; ++dd) {
        #pragma unroll
        for (int dh = 0; dh < 3; ++dh) {
            int ri = dd * 3 + dh;
            int z = d + dd - 1, y = h + dh - 1;
            bool rv = ((unsigned)z < 64u) && ((unsigned)y < 64u);
            const float* row = x + (z << 12) + (y << 6) + w0;
            n[ri][0] = (rv && w0 > 0)  ? row[-1] : 0.f;
            n[ri][1] = rv ? row[0] : 0.f;
            n[ri][2] = rv ? row[1] : 0.f;
            n[ri][3] = rv ? row[2] : 0.f;
            n[ri][4] = rv ? row[3] : 0.f;
            n[ri][5] = (rv && w0 < 60) ? row[4] : 0.f;
        }
    }

    float a0 = 0.f, a1 = 0.f, a2 = 0.f, a3 = 0.f;
    for (int c = 0; c < CH; ++c) {
        const float* wc = hw + c * 27;
        float bias = hb[c];
        float s0 = bias, s1 = bias, s2 = bias, s3 = bias;
        #pragma unroll
        for (int ri = 0; ri < 9; ++ri) {
            #pragma unroll
            for (int kx = 0; kx < 3; ++kx) {
                float wv = wc[ri * 3 + kx];
                s0 = fmaf(wv, n[ri][kx + 0], s0);
                s1 = fmaf(wv, n[ri][kx + 1], s1);
                s2 = fmaf(wv, n[ri][kx + 2], s2);
                s3 = fmaf(wv, n[ri][kx + 3], s3);
            }
        }
        float g = pw[c];
        a0 = fmaf(g, fmaxf(s0, 0.f), a0);
        a1 = fmaf(g, fmaxf(s1, 0.f), a1);
        a2 = fmaf(g, fmaxf(s2, 0.f), a2);
        a3 = fmaf(g, fmaxf(s3, 0.f), a3);
    }
    float4 o;
    o.x = 1.f / (1.f + __expf(-a0));
    o.y = 1.f / (1.f + __expf(-a1));
    o.z = 1.f / (1.f + __expf(-a2));
    o.w = 1.f / (1.f + __expf(-a3));
    int base = (b << 18) + (d << 12) + (h << 6) + w0;
    *(float4*)(p + base) = o;
}

// ================= fused propagation, ping-pong LDS cubes =================
// Cube 16z x 16y x 64x (full x width -> no x halo). Output tile 8z x 8y x 64x.
// Halo 4 in z,y; T iterations (T<=4), iteration it updates local z,y in
// [lo, 16-lo), lo = 5-T+it. Reads from Ain, writes to Aout (stale shell rows/
// planes copied) -> ONE barrier per iteration, zero intra-iteration hazards.
// Separable max: vertical(3 rows, float4) then horizontal window; z via
// register pipeline. LDS 2x64KB = 128 KB -> 1 block/CU.
#define ZC 16
#define YC 16
#define XC 64
#define PL (YC * XC)     // 1024 floats per z-plane
#define CUBE (ZC * PL)   // 16384 floats

__global__ __launch_bounds__(256, 1) void prop_kernel(
    const float* __restrict__ vin, int sstride,
    const float* __restrict__ rimg,   // r base = img + 2^18, sample stride 2^19
    const float* __restrict__ pbuf,   // p, sample stride 2^18
    float* __restrict__ vout,
    int T)
{
    __shared__ float LDS[2 * CUBE];   // 128 KB
    int blk = blockIdx.x;             // 256 blocks: 4b x 8tz x 8ty
    int b  = blk >> 6;
    int tz = ((blk >> 3) & 7) << 3;
    int ty = (blk & 7) << 3;

    const float* vb = vin  + (size_t)b * sstride;
    const float* rb = rimg + ((size_t)b << 19);
    const float* pb = pbuf + ((size_t)b << 18);
    float*       ob = vout + ((size_t)b << 18);

    int tid = threadIdx.x;
    int x4 = tid & 15, x0 = x4 << 2;
    int yy = tid >> 4;                // 0..15

    float* Ain  = LDS;
    float* Aout = LDS + CUBE;

    // ---- stage cube: thread (yy,x4) loads its float4 for all 16 z-planes
    {
        int gy = ty + yy - 4;
        bool vy = (unsigned)gy < 64u;
        const float* src = vb + gy * 64 + x0;
        #pragma unroll 4
        for (int z = 0; z < ZC; ++z) {
            int gz = tz + z - 4;
            float4 v = make_float4(NEG_INF, NEG_INF, NEG_INF, NEG_INF);
            if (vy && ((unsigned)gz < 64u))
                v = *(const float4*)(src + (gz << 12));
            *(float4*)(Ain + z * PL + yy * XC + x0) = v;
        }
    }
    __syncthreads();

    for (int it = 0; it < T; ++it) {
        int lo = 5 - T + it;
        int zs = lo - 1, ze = 17 - lo;   // active local z range [zs, ze)
        int nrow = ze - zs;              // = 18-2*lo rows, same range in y
        int y = zs + yy;
        bool act = yy < nrow;
        bool interior = (yy >= 1) && (yy < nrow - 1);
        int gy = ty + y - 4;
        bool vy = (unsigned)gy < 64u;
        bool lastit = (it == T - 1);
        int rbase = y * XC + x0;

        if (act) {
            if (interior && vy) {
                int goff = gy * 64 + x0;
                float4 q0, q1, q2, c1, c2;
                // rowy(z): vertical 3-row max then horizontal 3-window
                #define ROWY(zz, Q, C) {                                          \
                    const float* pz = Ain + (zz) * PL;                            \
                    float4 r0 = *(const float4*)(pz + rbase - XC);                \
                    float4 r1 = *(const float4*)(pz + rbase);                     \
                    float4 r2 = *(const float4*)(pz + rbase + XC);                \
                    float lm = NEG_INF, rm = NEG_INF;                             \
                    if (x4 > 0)                                                   \
                        lm = fmaxf(fmaxf(pz[rbase - XC - 1], pz[rbase - 1]),      \
                                   pz[rbase + XC - 1]);                           \
                    if (x4 < 15)                                                  \
                        rm = fmaxf(fmaxf(pz[rbase - XC + 4], pz[rbase + 4]),      \
                                   pz[rbase + XC + 4]);                           \
                    float4 cm;                                                    \
                    cm.x = fmaxf(fmaxf(r0.x, r1.x), r2.x);                        \
                    cm.y = fmaxf(fmaxf(r0.y, r1.y), r2.y);                        \
                    cm.z = fmaxf(fmaxf(r0.z, r1.z), r2.z);                        \
                    cm.w = fmaxf(fmaxf(r0.w, r1.w), r2.w);                        \
                    Q.x = fmaxf(lm, fmaxf(cm.x, cm.y));                           \
                    Q.y = fmaxf(cm.x, fmaxf(cm.y, cm.z));                         \
                    Q.z = fmaxf(cm.y, fmaxf(cm.z, cm.w));                         \
                    Q.w = fmaxf(fmaxf(cm.z, cm.w), rm);                           \
                    C = r1;                                                       \
                }
                { float4 cDummy; ROWY(zs, q0, cDummy); }
                ROWY(zs + 1, q1, c1);

                for (int z = zs + 1; z < ze - 1; ++z) {
                    ROWY(z + 1, q2, c2);
                    int gz = tz + z - 4;
                    float4 vn;
                    if ((unsigned)gz < 64u) {
                        int off = (gz << 12) + goff;
                        float4 pv = *(const float4*)(pb + off);
                        float4 rv = *(const float4*)(rb + off);
                        float4 m3;
                        m3.x = fmaxf(fmaxf(q0.x, q1.x), q2.x);
                        m3.y = fmaxf(fmaxf(q0.y, q1.y), q2.y);
                        m3.z = fmaxf(fmaxf(q0.z, q1.z), q2.z);
                        m3.w = fmaxf(fmaxf(q0.w, q1.w), q2.w);
                        vn.x = fmaxf(c1.x, fmaf(pv.x, m3.x - rv.x, rv.x));
                        vn.y = fmaxf(c1.y, fmaf(pv.y, m3.y - rv.y, rv.y));
                        vn.z = fmaxf(c1.z, fmaf(pv.z, m3.z - rv.z, rv.z));
                        vn.w = fmaxf(c1.w, fmaf(pv.w, m3.w - rv.w, rv.w));
                        if (lastit) *(float4*)(ob + off) = vn;
                    } else {
                        vn = c1;   // out-of-volume stays -inf
                    }
                    *(float4*)(Aout + z * PL + rbase) = vn;
                    q0 = q1; q1 = q2; c1 = c2;
                }
                // copy shell z-planes (stale values needed by next iteration)
                *(float4*)(Aout + zs * PL + rbase) =
                    *(const float4*)(Ain + zs * PL + rbase);
                *(float4*)(Aout + (ze - 1) * PL + rbase) =
                    *(const float4*)(Ain + (ze - 1) * PL + rbase);
                #undef ROWY
            } else {
                // shell row (or out-of-volume row): copy through
                for (int z = zs; z < ze; ++z)
                    *(float4*)(Aout + z * PL + rbase) =
                        *(const float4*)(Ain + z * PL + rbase);
            }
        }
        __syncthreads();
        float* tswap = Ain; Ain = Aout; Aout = tswap;
    }
}

extern "C" void kernel_launch(void* const* d_in, const int* in_sizes, int n_in,
                              void* d_out, int out_size, void* d_ws, size_t ws_size,
                              hipStream_t stream) {
    const float* img = (const float*)d_in[0];   // (4,2,64,64,64)
    const float* hw  = (const float*)d_in[1];   // (150,27)
    const float* hb  = (const float*)d_in[2];   // (150,)
    const float* pw  = (const float*)d_in[3];   // (150,)
    // d_in[4] = k (device scalar); reference fixes k=30.

    float* out = (float*)d_out;                      // X buffer (4 MB)
    float* p   = (float*)d_ws;                       // 4 MB
    float* vA  = (float*)((char*)d_ws + (4u << 20)); // Y buffer (4 MB)

    gate_kernel<<<1024, 256, 0, stream>>>(img, hw, hb, pw, p);

    const float* r0 = img + (1 << 18);  // r channel base, sample stride 2^19

    // 8 launches: 7*4 + 2 = 30 iterations. Ping-pong ends in d_out.
    prop_kernel<<<256, 256, 0, stream>>>(r0,  1 << 19, r0, p, vA,  4);  // img -> Y
    prop_kernel<<<256, 256, 0, stream>>>(vA,  1 << 18, r0, p, out, 4);  // Y -> X
    prop_kernel<<<256, 256, 0, stream>>>(out, 1 << 18, r0, p, vA,  4);
    prop_kernel<<<256, 256, 0, stream>>>(vA,  1 << 18, r0, p, out, 4);
    prop_kernel<<<256, 256, 0, stream>>>(out, 1 << 18, r0, p, vA,  4);
    prop_kernel<<<256, 256, 0, stream>>>(vA,  1 << 18, r0, p, out, 4);
    prop_kernel<<<256, 256, 0, stream>>>(out, 1 << 18, r0, p, vA,  4);
    prop_kernel<<<256, 256, 0, stream>>>(vA,  1 << 18, r0, p, out, 2);  // -> d_out
}

// Round 4
// 222.429 us; speedup vs baseline: 3.0864x; 1.7910x over previous
//
#include <hip/hip_runtime.h>
#include <math.h>

#define NEG_INF (-__builtin_inff())

typedef __attribute__((ext_vector_type(8))) short short8;
typedef __attribute__((ext_vector_type(4))) float f32x4;

__device__ __forceinline__ unsigned f2bf(float f) {   // fp32 -> bf16 bits (RNE)
    union { float f; unsigned u; } v; v.f = f;
    return (v.u + 0x7fffu + ((v.u >> 16) & 1u)) >> 16;
}

// ============ pad kernel: x channel -> zero-padded (4,66,66,66) bf16 ============
// Padded cell (z,y,x) = volume voxel (z-1,y-1,x-1); pad ring = 0 (conv SAME).
__global__ __launch_bounds__(256) void pad_kernel(
    const float* __restrict__ img, unsigned short* __restrict__ pad)
{
    int i = blockIdx.x * 256 + threadIdx.x;      // cell within one sample
    if (i >= 66 * 66 * 66) return;
    int b = blockIdx.y;
    int z = i / 4356;
    int rem = i - z * 4356;
    int y = rem / 66;
    int x = rem - y * 66;
    float v = 0.f;
    if (z >= 1 && z <= 64 && y >= 1 && y <= 64 && x >= 1 && x <= 64)
        v = img[((size_t)b << 19) + ((z - 1) << 12) + ((y - 1) << 6) + (x - 1)];
    pad[(size_t)b * 287496 + i] = (unsigned short)f2bf(v);
}

// ============ gate via MFMA: p = sigmoid(sum_c pw[c]*relu(conv(x)+hb[c])) ======
// GEMM: A[m=voxel][k=tap] * B[k][n=channel]; K=27 taps + bias row (k=27, A=1.0,
// B=hb) padded to 32; N=150 padded to 160 (10 tiles). 16x16x32 bf16 MFMA.
// A frag: lane holds A[m=lane&15][k=(lane>>4)*8+j]; B: B[k=(lane>>4)*8+j][n=lane&15];
// D: col=lane&15, row=(lane>>4)*4+reg.
__global__ __launch_bounds__(256, 2) void gate_mfma(
    const unsigned short* __restrict__ pad,
    const float* __restrict__ hw, const float* __restrict__ hb,
    const float* __restrict__ pw, float* __restrict__ p)
{
    const int lane = threadIdx.x & 63;
    const int col  = lane & 15;          // B: channel-in-tile; A: voxel m
    const int q    = lane >> 4;
    const int W    = blockIdx.x * 4 + (threadIdx.x >> 6);   // 4096 waves

    // ---- B fragments + pw, built once per wave
    int4  bfrag[10];
    float pwv[10];
    #pragma unroll
    for (int t = 0; t < 10; ++t) {
        int c = 16 * t + col;
        bool cv = c < 150;
        unsigned hv[8];
        #pragma unroll
        for (int j = 0; j < 8; ++j) {
            int k = 8 * q + j;
            float wv = 0.f;
            if (cv) {
                if (k < 27) wv = hw[c * 27 + k];
                else if (k == 27) wv = hb[c];
            }
            hv[j] = f2bf(wv);
        }
        bfrag[t] = make_int4(hv[0] | (hv[1] << 16), hv[2] | (hv[3] << 16),
                             hv[4] | (hv[5] << 16), hv[6] | (hv[7] << 16));
        pwv[t] = cv ? pw[c] : 0.f;
    }

    // ---- per-lane A-tap offsets into padded volume (loop-invariant)
    int offL[8]; unsigned cstA[8]; bool ldA[8];
    #pragma unroll
    for (int j = 0; j < 8; ++j) {
        int k = 8 * q + j;
        int dz = (k * 57) >> 9;          // k/9 for k<32
        int rem = k - 9 * dz;
        int dy = (rem * 171) >> 9;       // rem/3
        int dx = rem - 3 * dy;
        ldA[j]  = (k < 27);
        offL[j] = (k < 27) ? (dz * 4356 + dy * 66 + dx) : 0;
        cstA[j] = (k == 27) ? 0x3F80u : 0u;   // bias row: bf16(1.0)
    }

    // ---- 16 groups of 16 voxels per wave
    for (int i = 0; i < 16; ++i) {
        int g   = W * 16 + i;
        int x0  = (g & 3) << 4;
        int row = g >> 2;
        int y = row & 63, zz = (row >> 6) & 63, b = row >> 12;
        int abase = b * 287496 + zz * 4356 + y * 66 + x0 + col;

        unsigned av[8];
        #pragma unroll
        for (int j = 0; j < 8; ++j) {
            unsigned v = pad[abase + offL[j]];
            av[j] = ldA[j] ? v : cstA[j];
        }
        union { int4 i4; short8 s8; } af, bfu;
        af.i4 = make_int4(av[0] | (av[1] << 16), av[2] | (av[3] << 16),
                          av[4] | (av[5] << 16), av[6] | (av[7] << 16));

        const f32x4 zero = {0.f, 0.f, 0.f, 0.f};
        f32x4 rr[10];
        #pragma unroll
        for (int t = 0; t < 10; ++t) {
            bfu.i4 = bfrag[t];
            rr[t] = __builtin_amdgcn_mfma_f32_16x16x32_bf16(af.s8, bfu.s8, zero, 0, 0, 0);
        }
        float ax = 0.f, ay = 0.f, az = 0.f, aw = 0.f;
        #pragma unroll
        for (int t = 0; t < 10; ++t) {
            ax = fmaf(pwv[t], fmaxf(rr[t].x, 0.f), ax);
            ay = fmaf(pwv[t], fmaxf(rr[t].y, 0.f), ay);
            az = fmaf(pwv[t], fmaxf(rr[t].z, 0.f), az);
            aw = fmaf(pwv[t], fmaxf(rr[t].w, 0.f), aw);
        }
        #pragma unroll
        for (int m = 1; m < 16; m <<= 1) {
            ax += __shfl_xor(ax, m);
            ay += __shfl_xor(ay, m);
            az += __shfl_xor(az, m);
            aw += __shfl_xor(aw, m);
        }
        if (col == 0) {                  // rows 4q..4q+3 = x0+4q..x0+4q+3
            float4 o;
            o.x = 1.f / (1.f + __expf(-ax));
            o.y = 1.f / (1.f + __expf(-ay));
            o.z = 1.f / (1.f + __expf(-az));
            o.w = 1.f / (1.f + __expf(-aw));
            *(float4*)(p + (b << 18) + (zz << 12) + (y << 6) + x0 + 4 * q) = o;
        }
    }
}

// ============ fused propagation: in-place 48 KB LDS cube, compile-time T ======
// Cube 12z x 16y x 64x; output tile 4z x 8y x 64x (margins 4). Iteration it
// (lo=5-T+it) updates z,y in [lo, dim-lo); shrinking validity keeps it exact.
// Read phase -> registers, barrier, write phase, barrier. x-edge maxima via
// lane shuffles. Grid 512 -> 2 blocks/CU -> 2 waves/SIMD.
#define ZC 12
#define YC 16
#define PL 1024   // 16*64 floats per z-plane

template<int T>
__global__ __launch_bounds__(256, 2) void prop_kernel(
    const float* __restrict__ vin, int sstride,
    const float* __restrict__ rimg,   // r base = img + 2^18, sample stride 2^19
    const float* __restrict__ pbuf,   // p, sample stride 2^18
    float* __restrict__ vout)
{
    __shared__ float S[ZC * PL];
    int blk = blockIdx.x;             // 512 blocks: b(4) x tz(16) x ty(8)
    int b  = blk >> 7;
    int tz = ((blk >> 3) & 15) << 2;
    int ty = (blk & 7) << 3;

    const float* vb = vin  + (size_t)b * sstride;
    const float* rb = rimg + ((size_t)b << 19);
    const float* pb = pbuf + ((size_t)b << 18);
    float*       ob = vout + ((size_t)b << 18);

    int tid  = threadIdx.x;
    int x4   = tid & 15, x0 = x4 << 2;
    int yy   = tid >> 4;
    int lane = tid & 63;

    int gy = ty + yy - 4;
    bool vy = (unsigned)gy < 64u;

    // ---- stage
    {
        const float* src = vb + gy * 64 + x0;
        #pragma unroll
        for (int z = 0; z < ZC; ++z) {
            int gz = tz + z - 4;
            float4 v = make_float4(NEG_INF, NEG_INF, NEG_INF, NEG_INF);
            if (vy && ((unsigned)gz < 64u)) v = *(const float4*)(src + (gz << 12));
            *(float4*)(S + z * PL + yy * 64 + x0) = v;
        }
    }
    __syncthreads();

    int lbase = yy * 64 + x0;
    int goff  = gy * 64 + x0;

    // ROWY: vertical 3-row max (float4) + horizontal 3-window via shuffles
    #define ROWY(zz_, Q, C) {                                                  \
        const float* pz = S + (zz_) * PL + lbase;                              \
        float4 r0 = *(const float4*)(pz - 64);                                 \
        float4 r1 = *(const float4*)(pz);                                      \
        float4 r2 = *(const float4*)(pz + 64);                                 \
        float4 cm;                                                             \
        cm.x = fmaxf(fmaxf(r0.x, r1.x), r2.x);                                 \
        cm.y = fmaxf(fmaxf(r0.y, r1.y), r2.y);                                 \
        cm.z = fmaxf(fmaxf(r0.z, r1.z), r2.z);                                 \
        cm.w = fmaxf(fmaxf(r0.w, r1.w), r2.w);                                 \
        float lm = __shfl(cm.w, lane - 1);                                     \
        float rm = __shfl(cm.x, lane + 1);                                     \
        if (x4 == 0)  lm = NEG_INF;                                            \
        if (x4 == 15) rm = NEG_INF;                                            \
        Q.x = fmaxf(lm, fmaxf(cm.x, cm.y));                                    \
        Q.y = fmaxf(cm.x, fmaxf(cm.y, cm.z));                                  \
        Q.z = fmaxf(cm.y, fmaxf(cm.z, cm.w));                                  \
        Q.w = fmaxf(fmaxf(cm.z, cm.w), rm);                                    \
        C = r1;                                                                \
    }

    #pragma unroll
    for (int it = 0; it < T; ++it) {
        const int lo = 5 - T + it;
        bool act = (yy >= lo) && (yy < YC - lo);
        float4 vn[ZC - 2];
        if (act) {
            float4 q0, q1, q2, c1, c2, cd;
            ROWY(lo - 1, q0, cd);
            ROWY(lo,     q1, c1);
            #pragma unroll
            for (int z = lo; z < ZC - lo; ++z) {
                ROWY(z + 1, q2, c2);
                int gz = tz + z - 4;
                float4 r;
                if (vy && ((unsigned)gz < 64u)) {
                    int off = (gz << 12) + goff;
                    float4 pv = *(const float4*)(pb + off);
                    float4 rv = *(const float4*)(rb + off);
                    float4 m3;
                    m3.x = fmaxf(fmaxf(q0.x, q1.x), q2.x);
                    m3.y = fmaxf(fmaxf(q0.y, q1.y), q2.y);
                    m3.z = fmaxf(fmaxf(q0.z, q1.z), q2.z);
                    m3.w = fmaxf(fmaxf(q0.w, q1.w), q2.w);
                    r.x = fmaxf(c1.x, fmaf(pv.x, m3.x - rv.x, rv.x));
                    r.y = fmaxf(c1.y, fmaf(pv.y, m3.y - rv.y, rv.y));
                    r.z = fmaxf(c1.z, fmaf(pv.z, m3.z - rv.z, rv.z));
                    r.w = fmaxf(c1.w, fmaf(pv.w, m3.w - rv.w, rv.w));
                    if (it == T - 1) *(float4*)(ob + off) = r;
                } else {
                    r = c1;    // out-of-volume stays -inf / stale
                }
                vn[z - lo] = r;
                q0 = q1; q1 = q2; c1 = c2;
            }
        }
        __syncthreads();
        if (act) {
            #pragma unroll
            for (int z = lo; z < ZC - lo; ++z)
                *(float4*)(S + z * PL + lbase) = vn[z - lo];
        }
        __syncthreads();
    }
    #undef ROWY
}

extern "C" void kernel_launch(void* const* d_in, const int* in_sizes, int n_in,
                              void* d_out, int out_size, void* d_ws, size_t ws_size,
                              hipStream_t stream) {
    const float* img = (const float*)d_in[0];   // (4,2,64,64,64)
    const float* hw  = (const float*)d_in[1];   // (150,27)
    const float* hb  = (const float*)d_in[2];   // (150,)
    const float* pw  = (const float*)d_in[3];   // (150,)
    // d_in[4] = k (device scalar); reference fixes k=30.

    float* out = (float*)d_out;                      // X buffer (4 MB)
    float* p   = (float*)d_ws;                       // 4 MB
    float* vA  = (float*)((char*)d_ws + (4u << 20)); // Y buffer (4 MB)
    // padded bf16 volume (2.3 MB) shares the vA slot: used only before prop #1
    unsigned short* pad = (unsigned short*)((char*)d_ws + (4u << 20));

    pad_kernel<<<dim3(1124, 4), 256, 0, stream>>>(img, pad);
    gate_mfma<<<1024, 256, 0, stream>>>(pad, hw, hb, pw, p);

    const float* r0 = img + (1 << 18);  // r channel base, sample stride 2^19

    // 7*T4 + 1*T2 = 30 iterations; ping-pong ends in d_out.
    prop_kernel<4><<<512, 256, 0, stream>>>(r0,  1 << 19, r0, p, vA);   // img -> Y
    prop_kernel<4><<<512, 256, 0, stream>>>(vA,  1 << 18, r0, p, out);  // Y -> X
    prop_kernel<4><<<512, 256, 0, stream>>>(out, 1 << 18, r0, p, vA);
    prop_kernel<4><<<512, 256, 0, stream>>>(vA,  1 << 18, r0, p, out);
    prop_kernel<4><<<512, 256, 0, stream>>>(out, 1 << 18, r0, p, vA);
    prop_kernel<4><<<512, 256, 0, stream>>>(vA,  1 << 18, r0, p, out);
    prop_kernel<4><<<512, 256, 0, stream>>>(out, 1 << 18, r0, p, vA);
    prop_kernel<2><<<512, 256, 0, stream>>>(vA,  1 << 18, r0, p, out);  // -> d_out
}